// Round 11
// baseline (108.073 us; speedup 1.0000x reference)
//
#include <hip/hip_runtime.h>

// ExemplarNoAttention: logits[b,c] = log( sum_{e: label[e]==c} exp(-beta*d2[b,e]) + eps )
// d2[b,e] = ||x_b||^2 + ||e_e||^2 - 2<x_b,e_e>, clamped >= 0; beta = softplus(beta_raw).
//
// Round 11 = R9 (best: 100.1 us) attacking the newly-identified bottleneck: the
// per-CU LDS unit was saturated by 8-way bank-conflicted ds_read_b128 (LROW=72
// -> banks 4*(l15+quad) mod 32; ~29 us of LDS-unit occupancy ~= main's ~32 us,
// explaining why R7/R9/R10 latency/atomic/occupancy changes were all neutral).
//  (a) XOR-swizzled LDS image (64-half rows; 16B chunk q of row r at (q^(r&7))*16)
//      -> reads and writes hit all 32 banks, conflict-free. Register staging kept
//      (R8 proved DMA's vmcnt(0) barrier drain costs more than it saves).
//  (b) 2-wide column blocking: each wave computes 32 b-cols (two B-frag sets,
//      two accumulators) -> total ds_read volume HALVED at same MFMA/VALU totals.
//  (c) onehot label A-frags precomputed in prep (oh_pre, 1.6 MB, L2-resident)
//      -> removes the label LDS path and ~12 VALU/subtile from main.
// Segment-sum stays the onehot-MFMA; contention-free private partial stores;
// reduce+log finalize. Harness floor ~60 us (268 MB d_ws poison fill + restores).

#define NB      1024
#define NE      50000
#define NE_PAD  50176    // 196 chunks * 256
#define NCHUNK  196
#define CROWS   256      // e-rows per chunk
#define KD      64
#define NC      10
#define SROWS   64       // e-rows per stage
#define NSTAGE  4        // 256 / SROWS

using half8   = __attribute__((ext_vector_type(8))) _Float16;  // 16x16x32 A/B frag (4 VGPRs)
using half4v  = __attribute__((ext_vector_type(4))) _Float16;  // 16x16x16 A/B frag (2 VGPRs)
using floatx4 = __attribute__((ext_vector_type(4))) float;

__device__ __forceinline__ float softplus_f(float x) {
  return (x > 20.f) ? x : log1pf(__expf(x));
}

// ---------------------------------------------------------------------------
// prep: cast x/exemplars to fp16, cb = -beta*||x||^2, ce = -beta*||e||^2, AND
// precompute onehot label A-frags: oh_pre[sub][lane] = { label[sub*16+quad*4+j]
// == l15 } as half4 (A[m=class=l15][k=row-in-subtile=quad*4+j] for 16x16x16).
// 16 lanes/row, 16 rows/block, 3200 blocks (block b < 3136 also emits oh_pre[b]).
// Pad rows [NE, NE_PAD): ex_h = 0, ce = -1e30 (=> sim exactly 0; pad labels are
// clamped garbage but p=0 kills their contribution).
// ---------------------------------------------------------------------------
__global__ __launch_bounds__(256) void prep_kernel(
    const float* __restrict__ x, const float* __restrict__ ex,
    const int* __restrict__ labels, const float* __restrict__ beta_raw,
    _Float16* __restrict__ ex_h, float* __restrict__ ce,
    _Float16* __restrict__ x_h, float* __restrict__ cb,
    _Float16* __restrict__ oh_pre)
{
  const int tid = threadIdx.x;
  const float beta = softplus_f(beta_raw[0]);

  const int row = blockIdx.x * 16 + (tid >> 4);  // 3200*16 = 51200 = NE_PAD + NB
  const int l16 = tid & 15;

  if (row < NE_PAD) {
    float4 v = make_float4(0.f, 0.f, 0.f, 0.f);
    if (row < NE) v = ((const float4*)ex)[row * 16 + l16];
    half4v hv = { (_Float16)v.x, (_Float16)v.y, (_Float16)v.z, (_Float16)v.w };
    *(half4v*)(ex_h + (size_t)row * KD + l16 * 4) = hv;
    float s = v.x*v.x + v.y*v.y + v.z*v.z + v.w*v.w;
    #pragma unroll
    for (int m = 1; m < 16; m <<= 1) s += __shfl_xor(s, m, 64);
    if (l16 == 0) ce[row] = (row < NE) ? (-beta * s) : -1e30f;
  } else {
    const int rx = row - NE_PAD;  // [0, NB)
    float4 v = ((const float4*)x)[rx * 16 + l16];
    half4v hv = { (_Float16)v.x, (_Float16)v.y, (_Float16)v.z, (_Float16)v.w };
    *(half4v*)(x_h + (size_t)rx * KD + l16 * 4) = hv;
    float s = v.x*v.x + v.y*v.y + v.z*v.z + v.w*v.w;
    #pragma unroll
    for (int m = 1; m < 16; m <<= 1) s += __shfl_xor(s, m, 64);
    if (l16 == 0) cb[rx] = -beta * s;
  }

  // onehot A-frag for this block's 16-row subtile (blocks 0..3135)
  if (blockIdx.x < (NE_PAD / 16) && tid < 64) {
    const int l15  = tid & 15;
    const int quad = tid >> 4;
    const int base = min(blockIdx.x * 16 + quad * 4, NE - 4);  // clamp: pads killed by ce
    const int4 lb = *(const int4*)(labels + base);
    half4v oh;
    oh[0] = (lb.x == l15) ? (_Float16)1.f : (_Float16)0.f;
    oh[1] = (lb.y == l15) ? (_Float16)1.f : (_Float16)0.f;
    oh[2] = (lb.z == l15) ? (_Float16)1.f : (_Float16)0.f;
    oh[3] = (lb.w == l15) ? (_Float16)1.f : (_Float16)0.f;
    ((half4v*)oh_pre)[blockIdx.x * 64 + tid] = oh;
  }
}

// ---------------------------------------------------------------------------
// main: grid (8 btiles of 128 cols, 196 chunks of 256 e-rows), block = 4 waves.
// Wave w owns batch cols [btile*128 + 32w, +32) as TWO 16-col groups (two B-frag
// sets, two accumulators) -> A-frag ds_reads amortized over 32 cols.
// LDS: 2 x 8 KB XOR-swizzled stage images; register staging (thread t writes its
// two 16 B chunks q=2(t&3),2(t&3)+1 of row r=t>>2 at r*128 + (q^(r&7))*16 bytes).
// Per stage: prefetch next stage global->regs; load stage's ce/oh to regs;
// compute 4 subtiles from LDS; barrier; write regs->other buf; barrier.
// Subtile: ae0/ae1 from swizzled LDS (conflict-free); MFMA1 16x16x32 x2 per col
// group -> d[e][b]; p = exp(min(2*beta*d + cb + ce, 0)) fp16 (= 16x16x16 B-frag);
// MFMA2 vs precomputed onehot -> acc[c][b] in AGPRs.
// Flush: plain coalesced stores into part[chunk] (zero atomics, zero contention).
// ---------------------------------------------------------------------------
__global__ __launch_bounds__(256) void main_kernel(
    const _Float16* __restrict__ ex_h, const float* __restrict__ ce,
    const _Float16* __restrict__ x_h, const float* __restrict__ cb,
    const _Float16* __restrict__ oh_pre, const float* __restrict__ beta_raw,
    float* __restrict__ part)
{
  __shared__ _Float16 Ah[2][SROWS * KD];   // 2 x 8192 B swizzled stage images

  const int tid  = threadIdx.x;
  const int wave = tid >> 6;
  const int lane = tid & 63;
  const int l15  = lane & 15;
  const int quad = lane >> 4;

  const int btile = blockIdx.x;      // 0..7
  const int chunk = blockIdx.y;      // 0..195
  const int e0    = chunk * CROWS;
  const int bm    = btile * 128 + wave * 32;

  const float beta = softplus_f(beta_raw[0]);
  const float s2 = 2.f * beta;

  // two B-frag sets: col groups c0 = bm+l15, c1 = bm+16+l15
  const half8* xr0 = (const half8*)(x_h + (size_t)(bm + l15) * KD);
  const half8* xr1 = (const half8*)(x_h + (size_t)(bm + 16 + l15) * KD);
  const half8 bx00 = xr0[quad];
  const half8 bx01 = xr0[quad + 4];
  const half8 bx10 = xr1[quad];
  const half8 bx11 = xr1[quad + 4];
  const float cbl0 = cb[bm + l15];
  const float cbl1 = cb[bm + 16 + l15];

  // staging lane constants: thread t moves 32 B of row srow, chunks 2*scol, 2*scol+1
  const int srow = tid >> 2;
  const int scol = tid & 3;
  const int ssw  = srow & 7;
  const _Float16* gsrc = ex_h + (size_t)(e0 + srow) * KD + scol * 16;
  const int lofs0 = srow * KD + (((2 * scol)     ^ ssw) * 8);
  const int lofs1 = srow * KD + (((2 * scol + 1) ^ ssw) * 8);

  // ---- prologue: stage 0 global -> regs -> LDS buf 0 ----
  half8 pr0 = *(const half8*)(gsrc);
  half8 pr1 = *(const half8*)(gsrc + 8);
  *(half8*)(&Ah[0][lofs0]) = pr0;
  *(half8*)(&Ah[0][lofs1]) = pr1;
  __syncthreads();

  floatx4 acc0 = {0.f, 0.f, 0.f, 0.f};
  floatx4 acc1 = {0.f, 0.f, 0.f, 0.f};

  const int rsw = l15 & 7;   // read swizzle for this lane's A-frag rows

  #pragma unroll
  for (int st = 0; st < NSTAGE; ++st) {
    const int b = st & 1;

    // prefetch next stage into registers (vmcnt chain, independent of ds_reads)
    if (st + 1 < NSTAGE) {
      const _Float16* g = gsrc + (size_t)(st + 1) * SROWS * KD;
      pr0 = *(const half8*)(g);
      pr1 = *(const half8*)(g + 8);
    }

    // this stage's ce + onehot frags: register loads (L2-hot broadcasts)
    float4 ce4s[4]; half4v ohs[4];
    #pragma unroll
    for (int sub = 0; sub < 4; ++sub) {
      ce4s[sub] = *(const float4*)(ce + e0 + st * SROWS + sub * 16 + quad * 4);
      ohs[sub]  = ((const half4v*)oh_pre)[(size_t)(chunk * 16 + st * 4 + sub) * 64 + lane];
    }

    // compute 4 subtiles of 16 e-rows from swizzled LDS buf b
    #pragma unroll
    for (int sub = 0; sub < 4; ++sub) {
      const int rs = sub * 16 + l15;
      const half8 ae0 = *(const half8*)(&Ah[b][rs * KD + ((quad ^ rsw) * 8)]);
      const half8 ae1 = *(const half8*)(&Ah[b][rs * KD + (((quad + 4) ^ rsw) * 8)]);

      floatx4 d0 = {0.f, 0.f, 0.f, 0.f};
      d0 = __builtin_amdgcn_mfma_f32_16x16x32_f16(ae0, bx00, d0, 0, 0, 0);
      d0 = __builtin_amdgcn_mfma_f32_16x16x32_f16(ae1, bx01, d0, 0, 0, 0);
      floatx4 d1 = {0.f, 0.f, 0.f, 0.f};
      d1 = __builtin_amdgcn_mfma_f32_16x16x32_f16(ae0, bx10, d1, 0, 0, 0);
      d1 = __builtin_amdgcn_mfma_f32_16x16x32_f16(ae1, bx11, d1, 0, 0, 0);

      const float4 ce4 = ce4s[sub];
      const float cef[4] = { ce4.x, ce4.y, ce4.z, ce4.w };
      half4v p0, p1;
      #pragma unroll
      for (int r = 0; r < 4; ++r) {
        const float t0 = fminf(fmaf(s2, d0[r], cbl0 + cef[r]), 0.f);  // -beta*max(d2,0)
        const float t1 = fminf(fmaf(s2, d1[r], cbl1 + cef[r]), 0.f);
        p0[r] = (_Float16)__expf(t0);
        p1[r] = (_Float16)__expf(t1);
      }

      acc0 = __builtin_amdgcn_mfma_f32_16x16x16f16(ohs[sub], p0, acc0, 0, 0, 0);
      acc1 = __builtin_amdgcn_mfma_f32_16x16x16f16(ohs[sub], p1, acc1, 0, 0, 0);
    }

    if (st + 1 < NSTAGE) {
      __syncthreads();
      const int nb = (st + 1) & 1;
      *(half8*)(&Ah[nb][lofs0]) = pr0;
      *(half8*)(&Ah[nb][lofs1]) = pr1;
      __syncthreads();
    }
  }

  // Flush: acc holds class_part[c = quad*4+r][b]. Private per-chunk slice,
  // plain stores, zero contention (each cell written by exactly one block).
  float* dst = part + (size_t)chunk * (NB * NC);
  #pragma unroll
  for (int r = 0; r < 4; ++r) {
    const int c = quad * 4 + r;
    if (c < NC) {
      dst[(bm + l15) * NC + c]      = acc0[r];
      dst[(bm + 16 + l15) * NC + c] = acc1[r];
    }
  }
}

// ---------------------------------------------------------------------------
// reduce+finalize: out[bc] = log( sum_k part[k][bc] + eps ). Coalesced per
// k-pass; ~8 MB L2/L3-hot. Fixed summation order -> deterministic.
// ---------------------------------------------------------------------------
__global__ __launch_bounds__(256) void reduce_kernel(
    const float* __restrict__ part, float* __restrict__ out)
{
  const int bc = blockIdx.x * 256 + threadIdx.x;
  if (bc < NB * NC) {
    float s = 0.f;
    #pragma unroll 7
    for (int k = 0; k < NCHUNK; ++k) s += part[(size_t)k * (NB * NC) + bc];
    out[bc] = __logf(s + 1e-12f);
  }
}

extern "C" void kernel_launch(void* const* d_in, const int* in_sizes, int n_in,
                              void* d_out, int out_size, void* d_ws, size_t ws_size,
                              hipStream_t stream)
{
  const float* x        = (const float*)d_in[0];
  const float* ex       = (const float*)d_in[1];
  const int*   labels   = (const int*)d_in[2];
  const float* beta_raw = (const float*)d_in[3];
  float* out = (float*)d_out;

  // Workspace layout (~16.4 MB total):
  char* ws = (char*)d_ws;
  _Float16* ex_h   = (_Float16*)ws;             // 50176*64*2 = 6,422,528 B
  float*    ce     = (float*)(ws + 6422528);    //   200,704 B
  _Float16* x_h    = (_Float16*)(ws + 6623232); //   131,072 B
  float*    cb     = (float*)(ws + 6754304);    //     4,096 B
  _Float16* oh_pre = (_Float16*)(ws + 6758400); // 3136*64*8 = 1,605,632 B
  float*    part   = (float*)(ws + 8364032);    // 196*10240*4 = 8,028,160 B (end: 16,392,192)

  prep_kernel<<<3200, 256, 0, stream>>>(x, ex, labels, beta_raw,
                                        ex_h, ce, x_h, cb, oh_pre);
  dim3 g(8, 196);
  main_kernel<<<g, 256, 0, stream>>>(ex_h, ce, x_h, cb, oh_pre, beta_raw, part);
  reduce_kernel<<<40, 256, 0, stream>>>(part, out);
}

// Round 12
// 107.290 us; speedup vs baseline: 1.0073x; 1.0073x over previous
//
#include <hip/hip_runtime.h>

// ExemplarNoAttention: logits[b,c] = log( sum_{e: label[e]==c} exp(-beta*d2[b,e]) + eps )
// d2[b,e] = ||x_b||^2 + ||e_e||^2 - 2<x_b,e_e>, clamped >= 0; beta = softplus(beta_raw).
//
// Round 12: attack the ONLY invariant across six neutral rewrites (R6-R11): the
// stage-barrier cadence. All prior mains staged ~8 KB -> ~250 cyc compute ->
// block-wide barrier with vmcnt(0) drain (~500+ cyc L3 latency), repeated 8-16x
// per block with all waves stalling together. R12: one block = one WHOLE 256-row
// chunk (32 KB LDS image, swizzled) x 256 batch cols. All staging loads issued
// at once (8 in-flight/thread), ONE barrier per block total, then 16 row-subtiles
// x 4 col-groups of pure LDS compute. ex_h read 4x total (vs 16x); barriers per
// unit work cut 32x. Grid 784 = ~3 blocks/CU (LDS 41 KB).
// prep (incl. precomputed onehot frags) and reduce kernels: R11 verbatim.
// Harness floor ~58 us (268 MB d_ws poison fill + restores) is untouchable.

#define NB      1024
#define NE      50000
#define NE_PAD  50176    // 196 chunks * 256
#define NCHUNK  196
#define CROWS   256      // e-rows per chunk (whole chunk in LDS)
#define KD      64
#define NC      10

using half8   = __attribute__((ext_vector_type(8))) _Float16;  // 16x16x32 A/B frag (4 VGPRs)
using half4v  = __attribute__((ext_vector_type(4))) _Float16;  // 16x16x16 A/B frag (2 VGPRs)
using floatx4 = __attribute__((ext_vector_type(4))) float;

__device__ __forceinline__ float softplus_f(float x) {
  return (x > 20.f) ? x : log1pf(__expf(x));
}

// ---------------------------------------------------------------------------
// prep (R11 verbatim): cast x/exemplars to fp16, cb = -beta*||x||^2,
// ce = -beta*||e||^2, and precomputed onehot label A-frags oh_pre[sub][lane].
// Pad rows [NE, NE_PAD): ex_h = 0, ce = -1e30 (sim exactly 0; pad oh garbage
// is killed by p=0).
// ---------------------------------------------------------------------------
__global__ __launch_bounds__(256) void prep_kernel(
    const float* __restrict__ x, const float* __restrict__ ex,
    const int* __restrict__ labels, const float* __restrict__ beta_raw,
    _Float16* __restrict__ ex_h, float* __restrict__ ce,
    _Float16* __restrict__ x_h, float* __restrict__ cb,
    _Float16* __restrict__ oh_pre)
{
  const int tid = threadIdx.x;
  const float beta = softplus_f(beta_raw[0]);

  const int row = blockIdx.x * 16 + (tid >> 4);  // 3200*16 = 51200 = NE_PAD + NB
  const int l16 = tid & 15;

  if (row < NE_PAD) {
    float4 v = make_float4(0.f, 0.f, 0.f, 0.f);
    if (row < NE) v = ((const float4*)ex)[row * 16 + l16];
    half4v hv = { (_Float16)v.x, (_Float16)v.y, (_Float16)v.z, (_Float16)v.w };
    *(half4v*)(ex_h + (size_t)row * KD + l16 * 4) = hv;
    float s = v.x*v.x + v.y*v.y + v.z*v.z + v.w*v.w;
    #pragma unroll
    for (int m = 1; m < 16; m <<= 1) s += __shfl_xor(s, m, 64);
    if (l16 == 0) ce[row] = (row < NE) ? (-beta * s) : -1e30f;
  } else {
    const int rx = row - NE_PAD;  // [0, NB)
    float4 v = ((const float4*)x)[rx * 16 + l16];
    half4v hv = { (_Float16)v.x, (_Float16)v.y, (_Float16)v.z, (_Float16)v.w };
    *(half4v*)(x_h + (size_t)rx * KD + l16 * 4) = hv;
    float s = v.x*v.x + v.y*v.y + v.z*v.z + v.w*v.w;
    #pragma unroll
    for (int m = 1; m < 16; m <<= 1) s += __shfl_xor(s, m, 64);
    if (l16 == 0) cb[rx] = -beta * s;
  }

  // onehot A-frag for this block's 16-row subtile (blocks 0..3135)
  if (blockIdx.x < (NE_PAD / 16) && tid < 64) {
    const int l15  = tid & 15;
    const int quad = tid >> 4;
    const int base = min(blockIdx.x * 16 + quad * 4, NE - 4);  // clamp: pads killed by ce
    const int4 lb = *(const int4*)(labels + base);
    half4v oh;
    oh[0] = (lb.x == l15) ? (_Float16)1.f : (_Float16)0.f;
    oh[1] = (lb.y == l15) ? (_Float16)1.f : (_Float16)0.f;
    oh[2] = (lb.z == l15) ? (_Float16)1.f : (_Float16)0.f;
    oh[3] = (lb.w == l15) ? (_Float16)1.f : (_Float16)0.f;
    ((half4v*)oh_pre)[blockIdx.x * 64 + tid] = oh;
  }
}

// ---------------------------------------------------------------------------
// main: grid 784 = 196 chunks x 4 col-groups of 256. Block = 4 waves; wave w
// owns cols [grp*256 + w*64, +64) as FOUR 16-col groups (4 B-frag sets + 4
// accumulators in registers). Whole 256-row chunk staged to LDS ONCE (XOR
// swizzle: 16B k-chunk q of row r at r*128 + (q^(r&7))*16 bytes -> conflict-free
// b128 reads/writes), plus ce (1 KB) and onehot frags (8 KB). ONE barrier.
// Then pure compute: 16 row-subtiles x 4 col-groups:
//   MFMA1 16x16x32 x2 -> d[e][b]; p = exp(min(2*beta*d + cb + ce, 0)) fp16
//   (= 16x16x16 B-frag); MFMA2 vs precomputed onehot -> acc[c][b] in AGPRs.
// Flush: plain coalesced stores into part[chunk] (zero atomics, zero contention).
// ---------------------------------------------------------------------------
__global__ __launch_bounds__(256) void main_kernel(
    const _Float16* __restrict__ ex_h, const float* __restrict__ ce,
    const _Float16* __restrict__ x_h, const float* __restrict__ cb,
    const _Float16* __restrict__ oh_pre, const float* __restrict__ beta_raw,
    float* __restrict__ part)
{
  __shared__ _Float16 Ah[CROWS * KD];        // 32768 B swizzled chunk image
  __shared__ float    CeS[CROWS];            //  1024 B
  __shared__ _Float16 OhS[16 * 64 * 4];      //  8192 B (half4v per lane per subtile)

  const int tid  = threadIdx.x;
  const int wave = tid >> 6;
  const int lane = tid & 63;
  const int l15  = lane & 15;
  const int quad = lane >> 4;

  const int chunk = blockIdx.x >> 2;          // 0..195
  const int grp   = blockIdx.x & 3;           // 0..3
  const int e0    = chunk * CROWS;
  const int bmw   = grp * 256 + wave * 64;    // this wave's first batch col

  const float beta = softplus_f(beta_raw[0]);
  const float s2 = 2.f * beta;

  // ---- staging: issue ALL global loads up front (8 row-loads + ce + oh) ----
  const int srow = tid >> 2;                  // 0..63
  const int scol = tid & 3;                   // 0..3 (two 16B chunks each)
  const _Float16* gsrc = ex_h + (size_t)(e0 + srow) * KD + scol * 16;
  half8 r0[4], r1[4];
  #pragma unroll
  for (int p = 0; p < 4; ++p) {               // 4 passes of 64 rows
    r0[p] = *(const half8*)(gsrc + (size_t)p * 64 * KD);
    r1[p] = *(const half8*)(gsrc + (size_t)p * 64 * KD + 8);
  }
  const float cev = ce[e0 + tid];
  // oh: 1024 half4v for this chunk; thread t copies 32 B (two int4)
  const int4* ohg = (const int4*)((const char*)oh_pre + (size_t)chunk * 8192 + tid * 32);
  const int4 oha = ohg[0];
  const int4 ohb = ohg[1];

  // B-frags: 4 col groups x 2 half8, loaded while staging loads are in flight
  half8 bx0[4], bx1[4];
  float cbl[4];
  #pragma unroll
  for (int g2 = 0; g2 < 4; ++g2) {
    const half8* xr = (const half8*)(x_h + (size_t)(bmw + g2 * 16 + l15) * KD);
    bx0[g2] = xr[quad];
    bx1[g2] = xr[quad + 4];
    cbl[g2] = cb[bmw + g2 * 16 + l15];
  }

  // ---- write staged data to LDS (swizzled), ONE barrier ----
  const int ssw = srow & 7;
  #pragma unroll
  for (int p = 0; p < 4; ++p) {
    const int rr = p * 64 + srow;             // rr&7 == srow&7
    *(half8*)(&Ah[rr * KD + (((2 * scol)     ^ ssw) * 8)]) = r0[p];
    *(half8*)(&Ah[rr * KD + (((2 * scol + 1) ^ ssw) * 8)]) = r1[p];
  }
  CeS[tid] = cev;
  ((int4*)OhS)[tid * 2]     = oha;
  ((int4*)OhS)[tid * 2 + 1] = ohb;
  __syncthreads();

  floatx4 acc[4] = { {0,0,0,0}, {0,0,0,0}, {0,0,0,0}, {0,0,0,0} };
  const int rsw = l15 & 7;                    // read swizzle key

  // ---- pure compute: 16 row-subtiles x 4 col-groups ----
  #pragma unroll 4
  for (int rsub = 0; rsub < 16; ++rsub) {
    const int rs = rsub * 16 + l15;           // rs&7 == l15&7
    const half8 ae0 = *(const half8*)(&Ah[rs * KD + ((quad ^ rsw) * 8)]);
    const half8 ae1 = *(const half8*)(&Ah[rs * KD + (((quad + 4) ^ rsw) * 8)]);
    const float4 ce4 = *(const float4*)(&CeS[rsub * 16 + quad * 4]);
    const half4v oh  = ((const half4v*)OhS)[rsub * 64 + lane];
    const float cef[4] = { ce4.x, ce4.y, ce4.z, ce4.w };

    #pragma unroll
    for (int g2 = 0; g2 < 4; ++g2) {
      floatx4 d = {0.f, 0.f, 0.f, 0.f};
      d = __builtin_amdgcn_mfma_f32_16x16x32_f16(ae0, bx0[g2], d, 0, 0, 0);
      d = __builtin_amdgcn_mfma_f32_16x16x32_f16(ae1, bx1[g2], d, 0, 0, 0);

      half4v p;
      #pragma unroll
      for (int r = 0; r < 4; ++r) {
        const float t = fminf(fmaf(s2, d[r], cbl[g2] + cef[r]), 0.f);  // -beta*max(d2,0)
        p[r] = (_Float16)__expf(t);
      }
      acc[g2] = __builtin_amdgcn_mfma_f32_16x16x16f16(oh, p, acc[g2], 0, 0, 0);
    }
  }

  // Flush: acc[g2] holds class_part[c = quad*4+r][b = bmw+g2*16+l15].
  // Private per-chunk slice, plain stores, zero contention.
  float* dst = part + (size_t)chunk * (NB * NC);
  #pragma unroll
  for (int g2 = 0; g2 < 4; ++g2) {
    #pragma unroll
    for (int r = 0; r < 4; ++r) {
      const int c = quad * 4 + r;
      if (c < NC) {
        dst[(bmw + g2 * 16 + l15) * NC + c] = acc[g2][r];
      }
    }
  }
}

// ---------------------------------------------------------------------------
// reduce+finalize: out[bc] = log( sum_k part[k][bc] + eps ). Coalesced per
// k-pass; ~8 MB L2/L3-hot. Fixed summation order -> deterministic.
// ---------------------------------------------------------------------------
__global__ __launch_bounds__(256) void reduce_kernel(
    const float* __restrict__ part, float* __restrict__ out)
{
  const int bc = blockIdx.x * 256 + threadIdx.x;
  if (bc < NB * NC) {
    float s = 0.f;
    #pragma unroll 7
    for (int k = 0; k < NCHUNK; ++k) s += part[(size_t)k * (NB * NC) + bc];
    out[bc] = __logf(s + 1e-12f);
  }
}

extern "C" void kernel_launch(void* const* d_in, const int* in_sizes, int n_in,
                              void* d_out, int out_size, void* d_ws, size_t ws_size,
                              hipStream_t stream)
{
  const float* x        = (const float*)d_in[0];
  const float* ex       = (const float*)d_in[1];
  const int*   labels   = (const int*)d_in[2];
  const float* beta_raw = (const float*)d_in[3];
  float* out = (float*)d_out;

  // Workspace layout (~16.4 MB total):
  char* ws = (char*)d_ws;
  _Float16* ex_h   = (_Float16*)ws;             // 50176*64*2 = 6,422,528 B
  float*    ce     = (float*)(ws + 6422528);    //   200,704 B
  _Float16* x_h    = (_Float16*)(ws + 6623232); //   131,072 B
  float*    cb     = (float*)(ws + 6754304);    //     4,096 B
  _Float16* oh_pre = (_Float16*)(ws + 6758400); // 3136*64*8 = 1,605,632 B
  float*    part   = (float*)(ws + 8364032);    // 196*10240*4 = 8,028,160 B (end: 16,392,192)

  prep_kernel<<<3200, 256, 0, stream>>>(x, ex, labels, beta_raw,
                                        ex_h, ce, x_h, cb, oh_pre);
  main_kernel<<<784, 256, 0, stream>>>(ex_h, ce, x_h, cb, oh_pre, beta_raw, part);
  reduce_kernel<<<40, 256, 0, stream>>>(part, out);
}